// Round 1
// baseline (309.377 us; speedup 1.0000x reference)
//
#include <hip/hip_runtime.h>
#include <hip/hip_bf16.h>

// The reference ends with log_softmax over a size-1 axis ([N,1] -> axis=-1),
// which is identically zero for any input. The whole DCRNN stack is therefore
// dead code w.r.t. the output. Correct output = 250000 fp32 zeros.
//
// Kernel: vectorized zero-fill of d_out. Memory floor: 1 MB write (~0.16 us
// at 6.3 TB/s); actual time is launch-overhead bound.

__global__ void RecurrentGCN_zero_out(float* __restrict__ out, int n) {
    const int n4 = n >> 2;                       // number of float4 chunks
    float4* __restrict__ out4 = reinterpret_cast<float4*>(out);
    const int stride = gridDim.x * blockDim.x;
    for (int i = blockIdx.x * blockDim.x + threadIdx.x; i < n4; i += stride) {
        out4[i] = make_float4(0.0f, 0.0f, 0.0f, 0.0f);
    }
    // Tail (dead for n = 250000, kept for generality)
    const int tail_start = n4 << 2;
    for (int i = tail_start + blockIdx.x * blockDim.x + threadIdx.x; i < n;
         i += stride) {
        out[i] = 0.0f;
    }
}

extern "C" void kernel_launch(void* const* d_in, const int* in_sizes, int n_in,
                              void* d_out, int out_size, void* d_ws, size_t ws_size,
                              hipStream_t stream) {
    (void)d_in; (void)in_sizes; (void)n_in; (void)d_ws; (void)ws_size;
    float* out = reinterpret_cast<float*>(d_out);
    const int threads = 256;
    // 62500 float4 stores; 256 blocks x 256 threads covers it in one pass.
    const int blocks = 256;
    RecurrentGCN_zero_out<<<blocks, threads, 0, stream>>>(out, out_size);
}